// Round 5
// baseline (528.372 us; speedup 1.0000x reference)
//
#include <hip/hip_runtime.h>
#include <stdint.h>

#define NFFT    1024
#define MROWS   32768
#define GRID    2048
#define RSTRIDE (GRID * 4)    // 4 waves/block

// pad 2 complex per 16 -> row stride 18 complex = 144 B (16B-aligned).
// All exchange patterns verified conflict-free at the 64-lane baseline.
__device__ __forceinline__ int P2(int i) { return i + 2 * (i >> 4); }

// in-place complex DFT4 (forward); legs (a,b,c,d) -> outputs k=0..3
__device__ __forceinline__ void dft4(float& ar, float& ai, float& br_, float& bi_,
                                     float& cr, float& ci, float& dr, float& di) {
  const float t0r = ar + cr,  t0i = ai + ci;
  const float t1r = ar - cr,  t1i = ai - ci;
  const float t2r = br_ + dr, t2i = bi_ + di;
  const float t3r = bi_ - di, t3i = dr - br_;   // -i*(b-d)
  ar  = t0r + t2r; ai  = t0i + t2i;
  br_ = t1r + t3r; bi_ = t1i + t3i;
  cr  = t0r - t2r; ci  = t0i - t2i;
  dr  = t1r - t3r; di  = t1i - t3i;
}

__device__ __forceinline__ void cmul(float& xr, float& xi, float c, float s) {
  const float r = xr * c - xi * s;
  xi = xr * s + xi * c;
  xr = r;
}

// Batched 1024-pt complex forward FFT. One WAVE per row, 16 complex/thread,
// radix-4 x5 grouped [s0 s1 | X | s2 s3 | X | s4], zero per-row barriers.
// This round: next-row global prefetch issued right after stage 0 (latency
// hidden under stages 1-4); b128 exchange-1 writes + stage-4 reads via the
// 2-per-16 pad; interleaved float2 twiddle table; bias in registers.
__global__ void __launch_bounds__(256, 4)
fft1024(const float* __restrict__ xr, const float* __restrict__ xi,
        const float* __restrict__ wr, const float* __restrict__ wi,
        const float* __restrict__ br, const float* __restrict__ bi,
        float* __restrict__ out) {
  __shared__ __align__(16) float2 tw2[256];        // W^n interleaved, 2 KB
  __shared__ __align__(16) float lds[4 * 2304];    // 4 waves x 1152 complex

  const int tid = threadIdx.x;
  const int w   = tid >> 6;
  const int t   = tid & 63;
  float* buf = lds + w * 2304;
  const int b  = t & 15;                   // t = 16a + b
  const int a  = t >> 4;
  const int t4 = t << 2;

  // ---- twiddle table (only barrier in the kernel) ----
  tw2[tid] = make_float2(wr[NFFT + tid], wi[NFFT + tid]);
  __syncthreads();

  // ---- stage-1 twiddles W^(64*qm), qm in {1,2,3,4,6,9}: wave-uniform ----
  const float u1r = wr[NFFT +  64], u1i = wi[NFFT +  64];
  const float u2r = wr[NFFT + 128], u2i = wi[NFFT + 128];
  const float u3r = wr[NFFT + 192], u3i = wi[NFFT + 192];
  const float u4r = wr[NFFT + 256], u4i = wi[NFFT + 256];
  const float u6r = wr[NFFT + 384], u6i = wi[NFFT + 384];
  const float u9r = wr[NFFT + 576], u9i = wi[NFFT + 576];

  // ---- bias, folded, loop-invariant: lane writes cols 4t+m+256k ----
  float badd_r[4][4], badd_i[4][4];        // [k][m]
#pragma unroll
  for (int k = 0; k < 4; ++k) {
    const float4 fb = *(const float4*)(br + t4 + 256 * k);
    const float4 gb = *(const float4*)(bi + t4 + 256 * k);
    badd_r[k][0] = fb.x - gb.x; badd_i[k][0] = fb.x + gb.x;
    badd_r[k][1] = fb.y - gb.y; badd_i[k][1] = fb.y + gb.y;
    badd_r[k][2] = fb.z - gb.z; badd_i[k][2] = fb.z + gb.z;
    badd_r[k][3] = fb.w - gb.w; badd_i[k][3] = fb.w + gb.w;
  }

  // ---- prefetch first row ----
  int row = blockIdx.x * 4 + w;
  float pvr[16], pvi[16];
  {
    const float* pr = xr + (size_t)row * NFFT;
    const float* px = xi + (size_t)row * NFFT;
#pragma unroll
    for (int e = 0; e < 16; ++e) { pvr[e] = pr[t + 64 * e]; pvi[e] = px[t + 64 * e]; }
  }

#pragma unroll 1                            // keep live state flat across rows
  for (; row < MROWS; ) {
    const int nxt = row + RSTRIDE;

    // ---- stage 0 (Ns=1), out-of-place pv -> v; frees pv for prefetch
    float vr[16], vi[16];
#pragma unroll
    for (int q = 0; q < 4; ++q) {
      float e0r = pvr[q],      e0i = pvi[q];
      float e1r = pvr[q + 4],  e1i = pvi[q + 4];
      float e2r = pvr[q + 8],  e2i = pvi[q + 8];
      float e3r = pvr[q + 12], e3i = pvi[q + 12];
      dft4(e0r, e0i, e1r, e1i, e2r, e2i, e3r, e3i);
      vr[q]      = e0r; vi[q]      = e0i;
      vr[q + 4]  = e1r; vi[q + 4]  = e1i;
      vr[q + 8]  = e2r; vi[q + 8]  = e2i;
      vr[q + 12] = e3r; vi[q + 12] = e3i;
    }

    // ---- issue next row's loads NOW; waitcnt lands at next iter's stage 0
    if (nxt < MROWS) {
      const float* pr = xr + (size_t)nxt * NFFT;
      const float* px = xi + (size_t)nxt * NFFT;
#pragma unroll
      for (int e = 0; e < 16; ++e) { pvr[e] = pr[t + 64 * e]; pvi[e] = px[t + 64 * e]; }
    }

    // ---- stage 1 (Ns=4): v[q+4m] *= W^(64qm)  (uniform SGPR constants)
    cmul(vr[5],  vi[5],  u1r, u1i);  cmul(vr[6],  vi[6],  u2r, u2i);
    cmul(vr[7],  vi[7],  u3r, u3i);
    cmul(vr[9],  vi[9],  u2r, u2i);  cmul(vr[10], vi[10], u4r, u4i);
    cmul(vr[11], vi[11], u6r, u6i);
    cmul(vr[13], vi[13], u3r, u3i);  cmul(vr[14], vi[14], u6r, u6i);
    cmul(vr[15], vi[15], u9r, u9i);
#pragma unroll
    for (int m = 0; m < 4; ++m)
      dft4(vr[4 * m], vi[4 * m], vr[1 + 4 * m], vi[1 + 4 * m],
           vr[2 + 4 * m], vi[2 + 4 * m], vr[3 + 4 * m], vi[3 + 4 * m]);

    // ---- exchange 1: buf[16t + u] = v[(u>>2)+4(u&3)]; phys 18t+u -> b128
#pragma unroll
    for (int jj = 0; jj < 8; ++jj) {
      const int u0 = 2 * jj, u1_ = 2 * jj + 1;
      const int e0 = (u0 >> 2) + 4 * (u0 & 3);
      const int e1 = (u1_ >> 2) + 4 * (u1_ & 3);
      float4 f;
      f.x = vr[e0]; f.y = vi[e0]; f.z = vr[e1]; f.w = vi[e1];
      *(float4*)&buf[2 * (18 * t + u0)] = f;
    }
    asm volatile("" ::: "memory");

    // ---- stage 2 (Ns=16): v[q+4r] = buf(t + 64q + 256r); tw W^(16rb) derived
#pragma unroll
    for (int q = 0; q < 4; ++q)
#pragma unroll
      for (int r = 0; r < 4; ++r) {
        const float2 f = *(const float2*)&buf[2 * P2(t + 64 * q + 256 * r)];
        vr[q + 4 * r] = f.x; vi[q + 4 * r] = f.y;
      }
    asm volatile("" ::: "memory");
    {
      const float2 T = tw2[16 * b];
      const float c1 = T.x, s1 = T.y;
      const float c2 = c1 * c1 - s1 * s1, s2 = 2.f * c1 * s1;
      const float c3 = c2 * c1 - s2 * s1, s3 = c2 * s1 + s2 * c1;
#pragma unroll
      for (int q = 0; q < 4; ++q) {
        cmul(vr[q + 4],  vi[q + 4],  c1, s1);
        cmul(vr[q + 8],  vi[q + 8],  c2, s2);
        cmul(vr[q + 12], vi[q + 12], c3, s3);
        dft4(vr[q], vi[q], vr[q + 4], vi[q + 4], vr[q + 8], vi[q + 8], vr[q + 12], vi[q + 12]);
      }
    }

    // ---- stage 3 (Ns=64): v[q+4k2] *= W^(4q(b+16k2)), derived from q=1
#pragma unroll
    for (int k2 = 0; k2 < 4; ++k2) {
      const float2 T = tw2[4 * (b + 16 * k2)];
      const float c1 = T.x, s1 = T.y;
      const float c2 = c1 * c1 - s1 * s1, s2 = 2.f * c1 * s1;
      const float c3 = c2 * c1 - s2 * s1, s3 = c2 * s1 + s2 * c1;
      cmul(vr[1 + 4 * k2], vi[1 + 4 * k2], c1, s1);
      cmul(vr[2 + 4 * k2], vi[2 + 4 * k2], c2, s2);
      cmul(vr[3 + 4 * k2], vi[3 + 4 * k2], c3, s3);
      dft4(vr[4 * k2], vi[4 * k2], vr[1 + 4 * k2], vi[1 + 4 * k2],
           vr[2 + 4 * k2], vi[2 + 4 * k2], vr[3 + 4 * k2], vi[3 + 4 * k2]);
    }

    // ---- exchange 2: buf[256a + b + 16k2 + 64k3] = v[k3 + 4k2]
#pragma unroll
    for (int k2 = 0; k2 < 4; ++k2)
#pragma unroll
      for (int k3 = 0; k3 < 4; ++k3)
        *(float2*)&buf[2 * P2(256 * a + b + 16 * k2 + 64 * k3)] =
            make_float2(vr[k3 + 4 * k2], vi[k3 + 4 * k2]);
    asm volatile("" ::: "memory");

    // ---- stage 4 (Ns=256): b128 reads v[m+4r] = buf(4t + m + 256r)
#pragma unroll
    for (int r = 0; r < 4; ++r)
#pragma unroll
      for (int jj = 0; jj < 2; ++jj) {
        const float4 f = *(const float4*)&buf[2 * P2(t4 + 2 * jj + 256 * r)];
        vr[2 * jj + 0 + 4 * r] = f.x; vi[2 * jj + 0 + 4 * r] = f.y;
        vr[2 * jj + 1 + 4 * r] = f.z; vi[2 * jj + 1 + 4 * r] = f.w;
      }
    asm volatile("" ::: "memory");          // next iter's exch-1 stays below
    {
      const float4 T01 = *(const float4*)&tw2[t4];       // W^(4t+0), W^(4t+1)
      const float4 T23 = *(const float4*)&tw2[t4 + 2];   // W^(4t+2), W^(4t+3)
      const float cc[4] = {T01.x, T01.z, T23.x, T23.z};
      const float ss[4] = {T01.y, T01.w, T23.y, T23.w};
#pragma unroll
      for (int m = 0; m < 4; ++m) {
        const float c1 = cc[m], s1 = ss[m];
        const float c2 = c1 * c1 - s1 * s1, s2 = 2.f * c1 * s1;
        const float c3 = c2 * c1 - s2 * s1, s3 = c2 * s1 + s2 * c1;
        cmul(vr[m + 4],  vi[m + 4],  c1, s1);
        cmul(vr[m + 8],  vi[m + 8],  c2, s2);
        cmul(vr[m + 12], vi[m + 12], c3, s3);
        dft4(vr[m], vi[m], vr[m + 4], vi[m + 4], vr[m + 8], vi[m + 8], vr[m + 12], vi[m + 12]);
      }
    }

    // ---- store + bias (registers): out[row][4t+m+256k] = v[m+4k] + badd
    float* o_r = out + (size_t)row * NFFT;
    float* o_i = out + (size_t)MROWS * NFFT + (size_t)row * NFFT;
#pragma unroll
    for (int k = 0; k < 4; ++k) {
      float4 R, I;
      R.x = vr[0 + 4 * k] + badd_r[k][0]; I.x = vi[0 + 4 * k] + badd_i[k][0];
      R.y = vr[1 + 4 * k] + badd_r[k][1]; I.y = vi[1 + 4 * k] + badd_i[k][1];
      R.z = vr[2 + 4 * k] + badd_r[k][2]; I.z = vi[2 + 4 * k] + badd_i[k][2];
      R.w = vr[3 + 4 * k] + badd_r[k][3]; I.w = vi[3 + 4 * k] + badd_i[k][3];
      *(float4*)(o_r + t4 + 256 * k) = R;
      *(float4*)(o_i + t4 + 256 * k) = I;
    }

    row = nxt;
  }
}

extern "C" void kernel_launch(void* const* d_in, const int* in_sizes, int n_in,
                              void* d_out, int out_size, void* d_ws, size_t ws_size,
                              hipStream_t stream) {
  const float* xr = (const float*)d_in[0];
  const float* xi = (const float*)d_in[1];
  const float* wr = (const float*)d_in[2];
  const float* wi = (const float*)d_in[3];
  const float* br = (const float*)d_in[4];
  const float* bi = (const float*)d_in[5];
  float* out = (float*)d_out;
  (void)in_sizes; (void)n_in; (void)out_size; (void)d_ws; (void)ws_size;

  fft1024<<<GRID, 256, 0, stream>>>(xr, xi, wr, wi, br, bi, out);
}